// Round 12
// baseline (415.094 us; speedup 1.0000x reference)
//
#include <hip/hip_runtime.h>
#include <hip/hip_bf16.h>

typedef short short8 __attribute__((ext_vector_type(8)));
typedef float floatx4 __attribute__((ext_vector_type(4)));

#define B_  256
#define T_  512
#define D_  64
#define L_  32
#define H_  128
#define PXS 516   // packed pre_x row stride (floats): [t][col*4+e], ~0 conflicts (R4/R5-verified)
#define HRS 136   // h_ring row stride in shorts: row bank offset 4 (R7-verified)

__device__ inline short f2bf(float f) {
    __hip_bfloat16 h = __float2bfloat16(f);
    union { __hip_bfloat16 h; short s; } u;
    u.h = h;
    return u.s;
}

__device__ inline float fast_sigmoid(float x) {
    return __builtin_amdgcn_rcpf(1.0f + __expf(-x));
}

__device__ inline float fast_tanh(float x) {
    float e = __expf(-2.0f * x);
    return 2.0f * __builtin_amdgcn_rcpf(1.0f + e) - 1.0f;
}

// One block per batch element; 256 threads = 4 WAVES (1 per SIMD); 1 block/CU.
// R7 duty structure (proven best) at half the wave count: wave w owns hidden
// cols [32w,32w+32) (two 16-col N-subtiles) x 4 gates -> 32 MFMAs/wave/step
// (same 128 boxes/CU, same 620-cyc pipe; one wave sustains a SIMD's 19.4
// cyc/MFMA rate). Rationale: per-step barrier rendezvous over 4 waves not 8,
// h-frag DS read traffic halved. VGPR ~300 legal at launch_bounds(256,1)
// (512-VGPR cap at 1 wave/SIMD).
__global__ __launch_bounds__(256, 1) void tamlstm_kernel(
    const float* __restrict__ xd,    // [B,T,D]
    const float* __restrict__ xs,    // [B,L]
    const float* __restrict__ Wih,   // [4H,D]
    const float* __restrict__ Whh,   // [4H,H]
    const float* __restrict__ Wzh,   // [4H,L]
    const float* __restrict__ bias,  // [4H]
    const float* __restrict__ Wout,  // [1,H]
    const float* __restrict__ bout,  // [1]
    float* __restrict__ out)         // [B,T]
{
    const int b    = blockIdx.x;
    const int tid  = threadIdx.x;
    const int w    = tid >> 6;    // wave 0..3
    const int lane = tid & 63;
    const int l15  = lane & 15;
    const int q    = lane >> 4;   // quad 0..3

    __shared__ __align__(16) float pre_x[16][PXS];   // 33 KB, wave-local r/w
    __shared__ __align__(16) short x_lds[16][72];    // 2.25 KB staged x window
    __shared__ __align__(16) short h_ring[32 * HRS]; // 8.5 KB padded bf16 ring
    __shared__ __align__(16) float out_lds[T_];      // 2 KB output buffer

    // zero ring row 0 only (h_{-1}); rows 1..31 are written before read
    if (tid < 64) ((int*)h_ring)[tid] = 0;

    const int col0 = (w << 5) + l15;      // first owned column
    const int col1 = col0 + 16;           // second owned column

    // ---- B-fragments (bf16) in registers ----
    // whh[e][n][s] element j = Whh[gate = col_n + 128e][k = 32s + 8q + j]
    short8 whh[4][2][4];  // [gate e][subtile n][k-chunk s], K=128
    short8 wih[4][2][2];  // [e][n][s], K=64
    #pragma unroll
    for (int e = 0; e < 4; ++e) {
        #pragma unroll
        for (int n = 0; n < 2; ++n) {
            const int g = col0 + (n << 4) + (e << 7);
            const float* rh = Whh + g * H_;
            #pragma unroll
            for (int s = 0; s < 4; ++s) {
                const float* p = rh + s * 32 + q * 8;
                short8 v;
                #pragma unroll
                for (int j = 0; j < 8; ++j) v[j] = f2bf(p[j]);
                whh[e][n][s] = v;
            }
            const float* ri = Wih + g * D_;
            #pragma unroll
            for (int s = 0; s < 2; ++s) {
                const float* p = ri + s * 32 + q * 8;
                short8 v;
                #pragma unroll
                for (int j = 0; j < 8; ++j) v[j] = f2bf(p[j]);
                wih[e][n][s] = v;
            }
        }
    }
    // W_out B-frag (broadcast over N: element j = wout[32s+8q+j])
    short8 wof[4];
    #pragma unroll
    for (int s = 0; s < 4; ++s) {
        short8 v;
        #pragma unroll
        for (int j = 0; j < 8; ++j) v[j] = f2bf(Wout[s * 32 + q * 8 + j]);
        wof[s] = v;
    }
    const float bo = bout[0];

    // ---- static part: bias + x_static @ Wzh^T (folded into pre_x at dump) ----
    float S[4][2];
    const float* xsb = xs + b * L_;
    #pragma unroll
    for (int e = 0; e < 4; ++e)
        #pragma unroll
        for (int n = 0; n < 2; ++n) {
            const int g = col0 + (n << 4) + (e << 7);
            const float* wz = Wzh + g * L_;
            float a = bias[g];
            for (int l = 0; l < L_; ++l) a += xsb[l] * wz[l];
            S[e][n] = a;
        }

    const float* xb = xd + (size_t)b * T_ * D_;
    const floatx4 ZERO = {0.f, 0.f, 0.f, 0.f};

    // ---- prologue: stage window 0, compute its pre_x, prefetch window 1 ----
    float4 xr;
    {
        float4 x4 = ((const float4*)xb)[tid];        // 4 floats per thread
        const int row = tid >> 4, cc = (tid & 15) * 4;
        uint2 pk;
        pk.x = (unsigned)(unsigned short)f2bf(x4.x) |
               ((unsigned)(unsigned short)f2bf(x4.y) << 16);
        pk.y = (unsigned)(unsigned short)f2bf(x4.z) |
               ((unsigned)(unsigned short)f2bf(x4.w) << 16);
        *(uint2*)&x_lds[row][cc] = pk;
    }
    __syncthreads();   // x_lds + ring row 0 visible
    xr = ((const float4*)(xb + 16 * D_))[tid];       // window 1 prefetch
    {
        floatx4 aw[4][2];
        #pragma unroll
        for (int s = 0; s < 2; ++s) {
            short8 af = *(const short8*)&x_lds[l15][s * 32 + q * 8];
            #pragma unroll
            for (int e = 0; e < 4; ++e)
                #pragma unroll
                for (int n = 0; n < 2; ++n)
                    aw[e][n] = __builtin_amdgcn_mfma_f32_16x16x32_bf16(af, wih[e][n][s],
                                   s == 0 ? ZERO : aw[e][n], 0, 0, 0);
        }
        #pragma unroll
        for (int n = 0; n < 2; ++n)
            #pragma unroll
            for (int r = 0; r < 4; ++r) {
                floatx4 pk = {aw[0][n][r] + S[0][n], aw[1][n][r] + S[1][n],
                              aw[2][n][r] + S[2][n], aw[3][n][r] + S[3][n]};
                *(floatx4*)&pre_x[q * 4 + r][(col0 + (n << 4)) << 2] = pk;
            }
    }

    float c0 = 0.0f, c1 = 0.0f;

    for (int t = 0; t < T_; ++t) {
        const int tw = t & 15;

        if (tw == 0 && t > 0) {
            // ---- wave-0: deferred out-dot for window W-1 via MFMA ----
            if (w == 0) {
                const int tp = t - 16;
                const short* ap = &h_ring[((tp + l15 + 1) & 31) * HRS];
                floatx4 d0 = __builtin_amdgcn_mfma_f32_16x16x32_bf16(
                                 *(const short8*)(ap + q * 8),      wof[0], ZERO, 0, 0, 0);
                floatx4 d1 = __builtin_amdgcn_mfma_f32_16x16x32_bf16(
                                 *(const short8*)(ap + 32 + q * 8), wof[1], ZERO, 0, 0, 0);
                floatx4 d2 = __builtin_amdgcn_mfma_f32_16x16x32_bf16(
                                 *(const short8*)(ap + 64 + q * 8), wof[2], ZERO, 0, 0, 0);
                floatx4 d3 = __builtin_amdgcn_mfma_f32_16x16x32_bf16(
                                 *(const short8*)(ap + 96 + q * 8), wof[3], ZERO, 0, 0, 0);
                floatx4 od = (d0 + d1) + (d2 + d3);
                if (l15 == 0) {
                    floatx4 ov = {od[0] + bo, od[1] + bo, od[2] + bo, od[3] + bo};
                    *(floatx4*)&out_lds[tp + q * 4] = ov;
                }
            }

            // ---- stage x window W (regs prefetched 16 steps ago) ----
            {
                const int row = tid >> 4, cc = (tid & 15) * 4;
                uint2 pk;
                pk.x = (unsigned)(unsigned short)f2bf(xr.x) |
                       ((unsigned)(unsigned short)f2bf(xr.y) << 16);
                pk.y = (unsigned)(unsigned short)f2bf(xr.z) |
                       ((unsigned)(unsigned short)f2bf(xr.w) << 16);
                *(uint2*)&x_lds[row][cc] = pk;
            }
            __syncthreads();  // x_lds visible (also orders out-dot ring reads)

            // prefetch window W+1 while MFMAs run
            if (t + 16 < T_) xr = ((const float4*)(xb + (t + 16) * D_))[tid];

            // ---- window MFMA (M=16 timesteps) + packed dump (wave-local) ----
            floatx4 aw[4][2];
            #pragma unroll
            for (int s = 0; s < 2; ++s) {
                short8 af = *(const short8*)&x_lds[l15][s * 32 + q * 8];
                #pragma unroll
                for (int e = 0; e < 4; ++e)
                    #pragma unroll
                    for (int n = 0; n < 2; ++n)
                        aw[e][n] = __builtin_amdgcn_mfma_f32_16x16x32_bf16(af, wih[e][n][s],
                                       s == 0 ? ZERO : aw[e][n], 0, 0, 0);
            }
            #pragma unroll
            for (int n = 0; n < 2; ++n)
                #pragma unroll
                for (int r = 0; r < 4; ++r) {
                    floatx4 pk = {aw[0][n][r] + S[0][n], aw[1][n][r] + S[1][n],
                                  aw[2][n][r] + S[2][n], aw[3][n][r] + S[3][n]};
                    *(floatx4*)&pre_x[q * 4 + r][(col0 + (n << 4)) << 2] = pk;
                }
        }

        // ---- recurrent MFMA: g += h_{t-1} @ Whh^T (8 indep 4-deep chains) ----
        const short8* hp = (const short8*)&h_ring[(t & 31) * HRS];
        short8 af0 = hp[q];
        short8 af1 = hp[4 + q];
        short8 af2 = hp[8 + q];
        short8 af3 = hp[12 + q];
        floatx4 px0 = *(const floatx4*)&pre_x[tw][col0 << 2];
        floatx4 px1 = *(const floatx4*)&pre_x[tw][col1 << 2];

        floatx4 acc[4][2];
        #pragma unroll
        for (int e = 0; e < 4; ++e)
            #pragma unroll
            for (int n = 0; n < 2; ++n)
                acc[e][n] = __builtin_amdgcn_mfma_f32_16x16x32_bf16(af0, whh[e][n][0], ZERO, 0, 0, 0);
        #pragma unroll
        for (int e = 0; e < 4; ++e)
            #pragma unroll
            for (int n = 0; n < 2; ++n)
                acc[e][n] = __builtin_amdgcn_mfma_f32_16x16x32_bf16(af1, whh[e][n][1], acc[e][n], 0, 0, 0);
        #pragma unroll
        for (int e = 0; e < 4; ++e)
            #pragma unroll
            for (int n = 0; n < 2; ++n)
                acc[e][n] = __builtin_amdgcn_mfma_f32_16x16x32_bf16(af2, whh[e][n][2], acc[e][n], 0, 0, 0);
        #pragma unroll
        for (int e = 0; e < 4; ++e)
            #pragma unroll
            for (int n = 0; n < 2; ++n)
                acc[e][n] = __builtin_amdgcn_mfma_f32_16x16x32_bf16(af3, whh[e][n][3], acc[e][n], 0, 0, 0);

        // ---- elementwise, two columns per lane ----
        {
            const float gi = acc[0][0].x + px0[0];
            const float gf = acc[1][0].x + px0[1];
            const float gg = acc[2][0].x + px0[2];
            const float go = acc[3][0].x + px0[3];
            const float is = fast_sigmoid(gi);
            const float fs = fast_sigmoid(gf);
            const float os = fast_sigmoid(go);
            const float tg = fast_tanh(gg);
            c0 = fs * c0 + is * tg;
            const float h0 = os * fast_tanh(c0);
            if (lane < 16) h_ring[((t + 1) & 31) * HRS + col0] = f2bf(h0);
        }
        {
            const float gi = acc[0][1].x + px1[0];
            const float gf = acc[1][1].x + px1[1];
            const float gg = acc[2][1].x + px1[2];
            const float go = acc[3][1].x + px1[3];
            const float is = fast_sigmoid(gi);
            const float fs = fast_sigmoid(gf);
            const float os = fast_sigmoid(go);
            const float tg = fast_tanh(gg);
            c1 = fs * c1 + is * tg;
            const float h1 = os * fast_tanh(c1);
            if (lane < 16) h_ring[((t + 1) & 31) * HRS + col1] = f2bf(h1);
        }

        __syncthreads();
    }

    // ---- epilogue: out-dot for final window (t' = 496..511), store out ----
    if (w == 0) {
        const int tp = T_ - 16;
        const short* ap = &h_ring[((tp + l15 + 1) & 31) * HRS];
        floatx4 d0 = __builtin_amdgcn_mfma_f32_16x16x32_bf16(
                         *(const short8*)(ap + q * 8),      wof[0], ZERO, 0, 0, 0);
        floatx4 d1 = __builtin_amdgcn_mfma_f32_16x16x32_bf16(
                         *(const short8*)(ap + 32 + q * 8), wof[1], ZERO, 0, 0, 0);
        floatx4 d2 = __builtin_amdgcn_mfma_f32_16x16x32_bf16(
                         *(const short8*)(ap + 64 + q * 8), wof[2], ZERO, 0, 0, 0);
        floatx4 d3 = __builtin_amdgcn_mfma_f32_16x16x32_bf16(
                         *(const short8*)(ap + 96 + q * 8), wof[3], ZERO, 0, 0, 0);
        floatx4 od = (d0 + d1) + (d2 + d3);
        if (l15 == 0) {
            floatx4 ov = {od[0] + bo, od[1] + bo, od[2] + bo, od[3] + bo};
            *(floatx4*)&out_lds[tp + q * 4] = ov;
        }
    }
    __syncthreads();
    out[b * T_ + tid]       = out_lds[tid];
    out[b * T_ + 256 + tid] = out_lds[256 + tid];
}

extern "C" void kernel_launch(void* const* d_in, const int* in_sizes, int n_in,
                              void* d_out, int out_size, void* d_ws, size_t ws_size,
                              hipStream_t stream) {
    const float* xd   = (const float*)d_in[0];
    const float* xs   = (const float*)d_in[1];
    const float* Wih  = (const float*)d_in[2];
    const float* Whh  = (const float*)d_in[3];
    const float* Wzh  = (const float*)d_in[4];
    const float* bias = (const float*)d_in[5];
    const float* Wout = (const float*)d_in[6];
    const float* bout = (const float*)d_in[7];
    float* o = (float*)d_out;
    hipLaunchKernelGGL(tamlstm_kernel, dim3(B_), dim3(256), 0, stream,
                       xd, xs, Wih, Whh, Wzh, bias, Wout, bout, o);
}

// Round 13
// 341.039 us; speedup vs baseline: 1.2171x; 1.2171x over previous
//
#include <hip/hip_runtime.h>
#include <hip/hip_bf16.h>

typedef short short8 __attribute__((ext_vector_type(8)));
typedef float floatx4 __attribute__((ext_vector_type(4)));

#define B_  256
#define T_  512
#define D_  64
#define L_  32
#define H_  128
#define PXS 516   // packed pre_x row stride (floats): [t][col*4+e], 0 conflicts (R4/R5-verified)
#define HRS 136   // h_ring row stride in shorts: 136*2B=272B -> row bank offset 4, conflict-free

__device__ inline short f2bf(float f) {
    __hip_bfloat16 h = __float2bfloat16(f);
    union { __hip_bfloat16 h; short s; } u;
    u.h = h;
    return u.s;
}

__device__ inline float fast_sigmoid(float x) {
    return __builtin_amdgcn_rcpf(1.0f + __expf(-x));
}

__device__ inline float fast_tanh(float x) {
    float e = __expf(-2.0f * x);
    return 2.0f * __builtin_amdgcn_rcpf(1.0f + e) - 1.0f;
}

// FINAL KERNEL (R7/R11, 289.8-292.6us; verified best across 12 rounds).
// One block per batch element; 512 threads = 8 waves (2/SIMD); 1 block/CU.
// Wave w owns hidden cols [16w,16w+16) x 4 gates -> i/f/g/o of a column in one
// lane's accumulators -> in-register EW; cell state c in registers.
// Window step (tw==0): wave-0 out-dot for window W-1 via MFMA (padded ring),
// stage x, barrier, prefetch next x, window MFMA, packed pre_x dump.
// Per step: 4 chained-MFMA gate accumulators, one b128 px read, EW, h ->
// padded ring, __syncthreads.
// Closed axes (all regressed): 4 waves (no co-resident wave to fill SIMD
// during serial phases), lgkm-only barriers, staggered/pre-barrier duties,
// per-step branch ladders, same-step global consume, unpadded MFMA ring,
// exp2 weight-fold (VALU not binding), fp8-MX (fails 8e-3), cross-CU N-split
// (cross-L2 latency). Plateau: ~1360 cyc/step = 620 MFMA-pipe floor + ~740
// serial recurrent-chain latency.
__global__ __launch_bounds__(512, 2) void tamlstm_kernel(
    const float* __restrict__ xd,    // [B,T,D]
    const float* __restrict__ xs,    // [B,L]
    const float* __restrict__ Wih,   // [4H,D]
    const float* __restrict__ Whh,   // [4H,H]
    const float* __restrict__ Wzh,   // [4H,L]
    const float* __restrict__ bias,  // [4H]
    const float* __restrict__ Wout,  // [1,H]
    const float* __restrict__ bout,  // [1]
    float* __restrict__ out)         // [B,T]
{
    const int b    = blockIdx.x;
    const int tid  = threadIdx.x;
    const int w    = tid >> 6;    // wave 0..7
    const int lane = tid & 63;
    const int l15  = lane & 15;
    const int q    = lane >> 4;   // quad 0..3

    __shared__ __align__(16) float pre_x[16][PXS];   // 33 KB, wave-local r/w
    __shared__ __align__(16) short x_lds[16][72];    // 2.25 KB staged x window
    __shared__ __align__(16) short h_ring[32 * HRS]; // 8.5 KB padded bf16 ring
    __shared__ __align__(16) float out_lds[T_];      // 2 KB output buffer

    // zero ring row 0 only (h_{-1}); rows 1..31 are written before read
    if (tid < 64) ((int*)h_ring)[tid] = 0;

    const int col = (w << 4) + l15;                 // hidden column 0..127

    // ---- B-fragments (bf16) in registers ----
    // B-frag element j = W[gate = col + 128e][k = 32s + 8q + j]
    short8 whh[4][4];  // [gate e][k-chunk s], K=128
    short8 wih[4][2];  // [e][s], K=64
    #pragma unroll
    for (int e = 0; e < 4; ++e) {
        const int g = col + (e << 7);
        const float* rh = Whh + g * H_;
        #pragma unroll
        for (int s = 0; s < 4; ++s) {
            const float* p = rh + s * 32 + q * 8;
            short8 v;
            #pragma unroll
            for (int j = 0; j < 8; ++j) v[j] = f2bf(p[j]);
            whh[e][s] = v;
        }
        const float* ri = Wih + g * D_;
        #pragma unroll
        for (int s = 0; s < 2; ++s) {
            const float* p = ri + s * 32 + q * 8;
            short8 v;
            #pragma unroll
            for (int j = 0; j < 8; ++j) v[j] = f2bf(p[j]);
            wih[e][s] = v;
        }
    }
    // W_out B-frag (broadcast over N: element j = wout[32s+8q+j])
    short8 wof[4];
    #pragma unroll
    for (int s = 0; s < 4; ++s) {
        short8 v;
        #pragma unroll
        for (int j = 0; j < 8; ++j) v[j] = f2bf(Wout[s * 32 + q * 8 + j]);
        wof[s] = v;
    }
    const float bo = bout[0];

    // ---- static part: bias + x_static @ Wzh^T (folded into pre_x at dump) ----
    float S[4];
    const float* xsb = xs + b * L_;
    #pragma unroll
    for (int e = 0; e < 4; ++e) {
        const int g = col + (e << 7);
        const float* wz = Wzh + g * L_;
        float a = bias[g];
        for (int l = 0; l < L_; ++l) a += xsb[l] * wz[l];
        S[e] = a;
    }

    const float* xb = xd + (size_t)b * T_ * D_;
    const floatx4 ZERO = {0.f, 0.f, 0.f, 0.f};      // hoisted acc init

    // ---- prologue: stage window 0, compute its pre_x, prefetch window 1 ----
    float xr0, xr1;
    {
        float2 x2 = ((const float2*)xb)[tid];
        unsigned pk = (unsigned)(unsigned short)f2bf(x2.x) |
                      ((unsigned)(unsigned short)f2bf(x2.y) << 16);
        const int e2 = tid * 2;
        *(unsigned*)&x_lds[e2 >> 6][e2 & 63] = pk;
    }
    __syncthreads();   // x_lds + ring row 0 visible
    {
        float2 x2 = ((const float2*)(xb + 16 * D_))[tid];   // window 1 prefetch
        xr0 = x2.x; xr1 = x2.y;
    }
    {
        floatx4 aw[4];
        #pragma unroll
        for (int s = 0; s < 2; ++s) {
            short8 af = *(const short8*)&x_lds[l15][s * 32 + q * 8];
            #pragma unroll
            for (int e = 0; e < 4; ++e)
                aw[e] = __builtin_amdgcn_mfma_f32_16x16x32_bf16(af, wih[e][s],
                            s == 0 ? ZERO : aw[e], 0, 0, 0);
        }
        #pragma unroll
        for (int r = 0; r < 4; ++r) {
            floatx4 pk = {aw[0][r] + S[0], aw[1][r] + S[1],
                          aw[2][r] + S[2], aw[3][r] + S[3]};
            *(floatx4*)&pre_x[q * 4 + r][col << 2] = pk;
        }
    }

    float c = 0.0f;

    for (int t = 0; t < T_; ++t) {
        const int tw = t & 15;

        if (tw == 0 && t > 0) {
            // ---- wave-0: deferred out-dot for window W-1 via MFMA ----
            if (w == 0) {
                const int tp = t - 16;
                const short* ap = &h_ring[((tp + l15 + 1) & 31) * HRS];
                floatx4 d0 = __builtin_amdgcn_mfma_f32_16x16x32_bf16(
                                 *(const short8*)(ap + q * 8),      wof[0], ZERO, 0, 0, 0);
                floatx4 d1 = __builtin_amdgcn_mfma_f32_16x16x32_bf16(
                                 *(const short8*)(ap + 32 + q * 8), wof[1], ZERO, 0, 0, 0);
                floatx4 d2 = __builtin_amdgcn_mfma_f32_16x16x32_bf16(
                                 *(const short8*)(ap + 64 + q * 8), wof[2], ZERO, 0, 0, 0);
                floatx4 d3 = __builtin_amdgcn_mfma_f32_16x16x32_bf16(
                                 *(const short8*)(ap + 96 + q * 8), wof[3], ZERO, 0, 0, 0);
                floatx4 od = (d0 + d1) + (d2 + d3);
                if (l15 == 0) {
                    floatx4 ov = {od[0] + bo, od[1] + bo, od[2] + bo, od[3] + bo};
                    *(floatx4*)&out_lds[tp + q * 4] = ov;
                }
            }

            // ---- stage x window W (regs prefetched 16 steps ago) ----
            {
                unsigned pk = (unsigned)(unsigned short)f2bf(xr0) |
                              ((unsigned)(unsigned short)f2bf(xr1) << 16);
                const int e2 = tid * 2;
                *(unsigned*)&x_lds[e2 >> 6][e2 & 63] = pk;
            }
            __syncthreads();  // x_lds visible (also orders out-dot ring reads)

            // prefetch window W+1 while MFMAs run
            if (t + 16 < T_) {
                float2 x2 = ((const float2*)(xb + (t + 16) * D_))[tid];
                xr0 = x2.x; xr1 = x2.y;
            }

            // ---- window MFMA (M=16 timesteps) + packed dump (wave-local) ----
            floatx4 aw[4];
            #pragma unroll
            for (int s = 0; s < 2; ++s) {
                short8 af = *(const short8*)&x_lds[l15][s * 32 + q * 8];
                #pragma unroll
                for (int e = 0; e < 4; ++e)
                    aw[e] = __builtin_amdgcn_mfma_f32_16x16x32_bf16(af, wih[e][s],
                                s == 0 ? ZERO : aw[e], 0, 0, 0);
            }
            #pragma unroll
            for (int r = 0; r < 4; ++r) {
                floatx4 pk = {aw[0][r] + S[0], aw[1][r] + S[1],
                              aw[2][r] + S[2], aw[3][r] + S[3]};
                *(floatx4*)&pre_x[q * 4 + r][col << 2] = pk;
            }
        }

        // ---- recurrent MFMA: g += h_{t-1} @ Whh^T (4 indep 4-deep chains) ----
        const short8* hp = (const short8*)&h_ring[(t & 31) * HRS];
        short8 af0 = hp[q];
        short8 af1 = hp[4 + q];
        short8 af2 = hp[8 + q];
        short8 af3 = hp[12 + q];
        floatx4 px = *(const floatx4*)&pre_x[tw][col << 2];

        floatx4 acc[4];
        #pragma unroll
        for (int e = 0; e < 4; ++e)
            acc[e] = __builtin_amdgcn_mfma_f32_16x16x32_bf16(af0, whh[e][0], ZERO, 0, 0, 0);
        #pragma unroll
        for (int e = 0; e < 4; ++e)
            acc[e] = __builtin_amdgcn_mfma_f32_16x16x32_bf16(af1, whh[e][1], acc[e], 0, 0, 0);
        #pragma unroll
        for (int e = 0; e < 4; ++e)
            acc[e] = __builtin_amdgcn_mfma_f32_16x16x32_bf16(af2, whh[e][2], acc[e], 0, 0, 0);
        #pragma unroll
        for (int e = 0; e < 4; ++e)
            acc[e] = __builtin_amdgcn_mfma_f32_16x16x32_bf16(af3, whh[e][3], acc[e], 0, 0, 0);

        // ---- elementwise (quads duplicate; S/bias already in px) ----
        const float gi = acc[0].x + px[0];
        const float gf = acc[1].x + px[1];
        const float gg = acc[2].x + px[2];
        const float go = acc[3].x + px[3];
        const float is = fast_sigmoid(gi);
        const float fs = fast_sigmoid(gf);
        const float os = fast_sigmoid(go);
        const float tg = fast_tanh(gg);
        c = fs * c + is * tg;
        const float h = os * fast_tanh(c);

        if (lane < 16) h_ring[((t + 1) & 31) * HRS + col] = f2bf(h);

        __syncthreads();
    }

    // ---- epilogue: out-dot for final window (t' = 496..511), store out ----
    if (w == 0) {
        const int tp = T_ - 16;
        const short* ap = &h_ring[((tp + l15 + 1) & 31) * HRS];
        floatx4 d0 = __builtin_amdgcn_mfma_f32_16x16x32_bf16(
                         *(const short8*)(ap + q * 8),      wof[0], ZERO, 0, 0, 0);
        floatx4 d1 = __builtin_amdgcn_mfma_f32_16x16x32_bf16(
                         *(const short8*)(ap + 32 + q * 8), wof[1], ZERO, 0, 0, 0);
        floatx4 d2 = __builtin_amdgcn_mfma_f32_16x16x32_bf16(
                         *(const short8*)(ap + 64 + q * 8), wof[2], ZERO, 0, 0, 0);
        floatx4 d3 = __builtin_amdgcn_mfma_f32_16x16x32_bf16(
                         *(const short8*)(ap + 96 + q * 8), wof[3], ZERO, 0, 0, 0);
        floatx4 od = (d0 + d1) + (d2 + d3);
        if (l15 == 0) {
            floatx4 ov = {od[0] + bo, od[1] + bo, od[2] + bo, od[3] + bo};
            *(floatx4*)&out_lds[tp + q * 4] = ov;
        }
    }
    __syncthreads();
    out[b * T_ + tid] = out_lds[tid];
}

extern "C" void kernel_launch(void* const* d_in, const int* in_sizes, int n_in,
                              void* d_out, int out_size, void* d_ws, size_t ws_size,
                              hipStream_t stream) {
    const float* xd   = (const float*)d_in[0];
    const float* xs   = (const float*)d_in[1];
    const float* Wih  = (const float*)d_in[2];
    const float* Whh  = (const float*)d_in[3];
    const float* Wzh  = (const float*)d_in[4];
    const float* bias = (const float*)d_in[5];
    const float* Wout = (const float*)d_in[6];
    const float* bout = (const float*)d_in[7];
    float* o = (float*)d_out;
    hipLaunchKernelGGL(tamlstm_kernel, dim3(B_), dim3(512), 0, stream,
                       xd, xs, Wih, Whh, Wzh, bias, Wout, bout, o);
}